// Round 5
// baseline (210.373 us; speedup 1.0000x reference)
//
#include <hip/hip_runtime.h>
#include <cstdint>
#include <cstddef>

typedef __bf16 bf16;
typedef __bf16 bf16x8 __attribute__((ext_vector_type(8)));
typedef float  f32x4  __attribute__((ext_vector_type(4)));

#define NB 4
#define SS 2048
#define EE 1024

// ---------------------------------------------------------------------------
// Async global->LDS, 16 B/lane. LDS dest = wave-uniform base + lane*16
// (m104/m108); global src is per-lane (swizzle applied on the src side).
// ---------------------------------------------------------------------------
static __device__ __forceinline__ void glds16(const bf16* g, void* l)
{
    __builtin_amdgcn_global_load_lds(
        (const __attribute__((address_space(1))) unsigned int*)g,
        (__attribute__((address_space(3))) unsigned int*)l,
        16, 0, 0);
}

// Bijective XCD-aware swizzle (all grids here have nwg % 8 == 0).
static __device__ __forceinline__ void swz_block(int& bx, int& by, int& bz)
{
    const int nx = gridDim.x, ny = gridDim.y;
    const int nwg = nx * ny * gridDim.z;
    int lin = blockIdx.x + nx * (blockIdx.y + ny * blockIdx.z);
    const int per = nwg >> 3;
    lin = (lin & 7) * per + (lin >> 3);
    bz = lin / (nx * ny);
    const int r = lin - bz * nx * ny;
    by = r / nx;
    bx = r - by * nx;
}

// ---------------------------------------------------------------------------
// Pipelined K-loop, BK=32, 512 threads = 8 waves (2M x 4N).
// Per-wave output = (M_REP*16) x (N_REP*16); BM = 32*M_REP, BN = 64*N_REP.
//
// LDS layout per region (A: BM rows, B: BN rows; 32 k each): paired-row
// swizzle. Logical (row r, 16B-chunk c4 in 0..3) lives at physical
// line = r>>1 (128 B lines), pos8 = (c4 + 4*(r&1)) ^ (line&7).
// Frag read (rows base+lr, chunk kq): pos8 = (kq + 4*(lr&1)) ^ (lr>>1) ->
// 16 lanes cover all 8 positions at exactly 2 lanes each = conflict-free
// (m136: 2-way free). Staging applies the inverse permutation to the GLOBAL
// source address, LDS dest stays linear (rule 21).
//
// Pipeline: NBUF=4 rotating buffers, depth-3 prefetch. While computing tile
// t from buf t%4, stage tile t+3 into buf (t+3)%4 (dead since tile t-1's
// boundary barrier). Boundary: s_waitcnt vmcnt(2L) -> tile t+1 landed,
// tiles t+2/t+3 stay in flight (T4: never drain in-loop). Tail: restage
// tile nt-1 into the dead rotating buffer (constant count), drain after.
// Two phases per tile: {B-frags + A-half0 reads | stage A | MFMA half0},
// {A-half1 reads | stage B | MFMA half1} with setprio around MFMA (T5).
// ---------------------------------------------------------------------------
template<int M_REP, int N_REP>
static __device__ __forceinline__ void kloopX(
    const bf16* __restrict__ A, const bf16* __restrict__ Bm,
    int lda, int ldb, int nt, char* lds, int m0, int n0, int tid,
    f32x4 acc[M_REP][N_REP])
{
    constexpr int BM = 32 * M_REP, BN = 64 * N_REP;
    constexpr int AREG = BM * 64;            // A region bytes
    constexpr int BUFB = (BM + BN) * 64;     // one pipeline buffer
    constexpr int LA = BM / 128, LB = BN / 128, L = LA + LB;
    constexpr int NBUF = 4;
    constexpr int MH = M_REP / 2;

    const int lane = tid & 63, w = tid >> 6;
    const int wm = w >> 2, wn = w & 3;
    const int lr = lane & 15, kq = lane >> 4;
    // swizzled per-lane byte offset within a region
    const int lby  = (lr >> 1) * 128 + (((kq + 4 * (lr & 1)) ^ (lr >> 1)) << 4);
    const int aoff = wm * (M_REP * 1024) + lby;
    const int boff = AREG + wn * (N_REP * 1024) + lby;
    const int wofs = w << 10;   // wave-uniform dest offset (64 lanes * 16 B)

    // staging sources (inverse-swizzled global addresses, constant per thread)
    const bf16* pA[LA];
    const bf16* pB[LB];
#pragma unroll
    for (int i = 0; i < LA; ++i) {
        const int idx = i * 512 + tid, line = idx >> 3, u = (idx & 7) ^ (line & 7);
        pA[i] = A + (size_t)(m0 + 2 * line + (u >> 2)) * lda + (u & 3) * 8;
    }
#pragma unroll
    for (int i = 0; i < LB; ++i) {
        const int idx = i * 512 + tid, line = idx >> 3, u = (idx & 7) ^ (line & 7);
        pB[i] = Bm + (size_t)(n0 + 2 * line + (u >> 2)) * ldb + (u & 3) * 8;
    }

    // ---- prologue: stage tiles 0..NBUF-2
#pragma unroll
    for (int p = 0; p < NBUF - 1; ++p) {
        char* d = lds + p * BUFB + wofs;
        const int kt = p * 32;
#pragma unroll
        for (int i = 0; i < LA; ++i) glds16(pA[i] + kt, d + i * 8192);
#pragma unroll
        for (int i = 0; i < LB; ++i) glds16(pB[i] + kt, d + AREG + i * 8192);
    }
    if constexpr (L == 3) asm volatile("s_waitcnt vmcnt(6)" ::: "memory");
    else                  asm volatile("s_waitcnt vmcnt(8)" ::: "memory");
    __builtin_amdgcn_sched_barrier(0);
    __builtin_amdgcn_s_barrier();
    __builtin_amdgcn_sched_barrier(0);

    int rb = 0, sb = NBUF - 1;
    for (int t = 0; t < nt; ++t) {
        char* la = lds + rb * BUFB;
        const int ts = (t + NBUF - 1 < nt) ? (t + NBUF - 1) : (nt - 1);
        const int kt = ts * 32;
        char* d = lds + sb * BUFB + wofs;

        // ---- phase 0: B frags + A half 0, stage A, MFMA half 0
        bf16x8 bg[N_REP], af[MH];
#pragma unroll
        for (int n = 0; n < N_REP; ++n)
            bg[n] = *(const bf16x8*)(la + boff + n * 1024);
#pragma unroll
        for (int m = 0; m < MH; ++m)
            af[m] = *(const bf16x8*)(la + aoff + m * 1024);
#pragma unroll
        for (int i = 0; i < LA; ++i) glds16(pA[i] + kt, d + i * 8192);

        __builtin_amdgcn_s_setprio(1);
#pragma unroll
        for (int m = 0; m < MH; ++m)
#pragma unroll
            for (int n = 0; n < N_REP; ++n)
                acc[m][n] = __builtin_amdgcn_mfma_f32_16x16x32_bf16(af[m], bg[n], acc[m][n], 0, 0, 0);
        __builtin_amdgcn_s_setprio(0);

        // ---- phase 1: A half 1, stage B, MFMA half 1
        bf16x8 ag[MH];
#pragma unroll
        for (int m = 0; m < MH; ++m)
            ag[m] = *(const bf16x8*)(la + aoff + (MH + m) * 1024);
#pragma unroll
        for (int i = 0; i < LB; ++i) glds16(pB[i] + kt, d + AREG + i * 8192);

        __builtin_amdgcn_s_setprio(1);
#pragma unroll
        for (int m = 0; m < MH; ++m)
#pragma unroll
            for (int n = 0; n < N_REP; ++n)
                acc[MH + m][n] = __builtin_amdgcn_mfma_f32_16x16x32_bf16(ag[m], bg[n], acc[MH + m][n], 0, 0, 0);
        __builtin_amdgcn_s_setprio(0);

        // ---- tile boundary: counted vmcnt (2 tiles in flight), never 0
        if (t < nt - 1) {
            if constexpr (L == 3) asm volatile("s_waitcnt vmcnt(6)" ::: "memory");
            else                  asm volatile("s_waitcnt vmcnt(8)" ::: "memory");
            __builtin_amdgcn_sched_barrier(0);
            __builtin_amdgcn_s_barrier();
            __builtin_amdgcn_sched_barrier(0);
        }
        rb = (rb + 1 == NBUF) ? 0 : rb + 1;
        sb = (sb + 1 == NBUF) ? 0 : sb + 1;
    }
    asm volatile("s_waitcnt vmcnt(0)" ::: "memory");  // drain dummy-tail loads
}

// ---------------------------------------------------------------------------
// K0: fp32 -> bf16 convert, 8 elems/thread, three tensors via blockIdx.y.
// ---------------------------------------------------------------------------
__global__ __launch_bounds__(256) void cvt3_kernel(
    const float* __restrict__ s0, const float* __restrict__ s1, const float* __restrict__ s2,
    bf16* __restrict__ d0, bf16* __restrict__ d1, bf16* __restrict__ d2, unsigned n)
{
    const float* s; bf16* d;
    if (blockIdx.y == 0)      { s = s0; d = d0; }
    else if (blockIdx.y == 1) { s = s1; d = d1; }
    else                      { s = s2; d = d2; }
    const size_t i = ((size_t)blockIdx.x * 256 + threadIdx.x) * 8;
    if (i >= n) return;
    const float4 f0 = *(const float4*)(s + i);
    const float4 f1 = *(const float4*)(s + i + 4);
    bf16x8 h;
    h[0] = (bf16)f0.x; h[1] = (bf16)f0.y; h[2] = (bf16)f0.z; h[3] = (bf16)f0.w;
    h[4] = (bf16)f1.x; h[5] = (bf16)f1.y; h[6] = (bf16)f1.z; h[7] = (bf16)f1.w;
    *(bf16x8*)(d + i) = h;
}

// ---------------------------------------------------------------------------
// K1: fused QKV projection. M=8192, N=K=1024, z selects q/k/v.
// BM=256 (M_REP=8), BN=128 (N_REP=2) -> 8x32x3 = 768 blocks = 3 CU-rounds.
// C/D 16x16 layout: col = lane&15, row = (lane>>4)*4 + j  [m89/m91].
// ---------------------------------------------------------------------------
__global__ __launch_bounds__(512, 2) void proj8(
    const bf16* __restrict__ qc, const bf16* __restrict__ kc, const bf16* __restrict__ vc,
    const bf16* __restrict__ Wc,
    const float* __restrict__ bq, const float* __restrict__ bk, const float* __restrict__ bv,
    bf16* __restrict__ qb, bf16* __restrict__ kb, bf16* __restrict__ vb)
{
    extern __shared__ char lds[];
    int bx, by, bz; swz_block(bx, by, bz);
    const bf16* A; const float* bias; bf16* out;
    if (bz == 0)      { A = qc; bias = bq; out = qb; }
    else if (bz == 1) { A = kc; bias = bk; out = kb; }
    else              { A = vc; bias = bv; out = vb; }
    const bf16* Bm = Wc + (size_t)bz * EE * EE;

    const int m0 = by * 256, n0 = bx * 128;
    const int tid = threadIdx.x;

    f32x4 acc[8][2];
#pragma unroll
    for (int m = 0; m < 8; ++m)
#pragma unroll
        for (int n = 0; n < 2; ++n) { acc[m][n][0] = 0.f; acc[m][n][1] = 0.f; acc[m][n][2] = 0.f; acc[m][n][3] = 0.f; }

    kloopX<8, 2>(A, Bm, EE, EE, EE / 32, lds, m0, n0, tid, acc);

    const int lane = tid & 63, w = tid >> 6, wm = w >> 2, wn = w & 3;
    const int lr = lane & 15, kq = lane >> 4;
#pragma unroll
    for (int n = 0; n < 2; ++n) {
        const int gcol = n0 + wn * 32 + n * 16 + lr;
        const float bb = bias[gcol];
#pragma unroll
        for (int m = 0; m < 8; ++m)
#pragma unroll
            for (int j = 0; j < 4; ++j) {
                const int grow = m0 + wm * 128 + m * 16 + kq * 4 + j;
                out[(size_t)grow * EE + gcol] = (bf16)(acc[m][n][j] + bb);
            }
    }
}

// ---------------------------------------------------------------------------
// K2: vb [b][s][e] -> vt [b][e][s]
// ---------------------------------------------------------------------------
__global__ __launch_bounds__(256) void transpose_kernel(const bf16* __restrict__ vb,
                                                        bf16* __restrict__ vt)
{
    __shared__ bf16 t[64][72];
    const int b  = blockIdx.z;
    const int s0 = blockIdx.x * 64, e0 = blockIdx.y * 64;
    const int tid = threadIdx.x;

    const bf16* src = vb + ((size_t)b * SS + s0) * EE + e0;
#pragma unroll
    for (int i = 0; i < 2; ++i) {
        const int c  = tid * 2 + i;
        const int r  = c >> 3;
        const int cc = (c & 7) * 8;
        *(uint4*)&t[r][cc] = *(const uint4*)&src[(size_t)r * EE + cc];
    }
    __syncthreads();

    bf16* dst = vt + ((size_t)b * EE + e0) * SS + s0;
    const int er  = tid >> 2;
    const int sc0 = (tid & 3) * 16;
    bf16 tmp[16];
#pragma unroll
    for (int k2 = 0; k2 < 16; ++k2) tmp[k2] = t[sc0 + k2][er];
    *(uint4*)&dst[(size_t)er * SS + sc0]     = *(uint4*)&tmp[0];
    *(uint4*)&dst[(size_t)er * SS + sc0 + 8] = *(uint4*)&tmp[8];
}

// ---------------------------------------------------------------------------
// K3: scores = (q.k)/32 + mask, bf16 out. M=N=2048, K=1024 per batch.
// BM=BN=256 (M_REP=8, N_REP=4) -> 8x8x4 = 256 blocks = 1 CU-round.
// ---------------------------------------------------------------------------
__global__ __launch_bounds__(512, 2) void scores8(const bf16* __restrict__ qb,
                                                  const bf16* __restrict__ kb,
                                                  const float* __restrict__ mask,
                                                  bf16* __restrict__ sc)
{
    extern __shared__ char lds[];
    int bx, by, bz; swz_block(bx, by, bz);
    const bf16* A  = qb + (size_t)bz * SS * EE;
    const bf16* Bm = kb + (size_t)bz * SS * EE;

    const int m0 = by * 256, n0 = bx * 256;
    const int tid = threadIdx.x;

    f32x4 acc[8][4];
#pragma unroll
    for (int m = 0; m < 8; ++m)
#pragma unroll
        for (int n = 0; n < 4; ++n) { acc[m][n][0] = 0.f; acc[m][n][1] = 0.f; acc[m][n][2] = 0.f; acc[m][n][3] = 0.f; }

    kloopX<8, 4>(A, Bm, EE, EE, EE / 32, lds, m0, n0, tid, acc);

    const int lane = tid & 63, w = tid >> 6, wm = w >> 2, wn = w & 3;
    const int lr = lane & 15, kq = lane >> 4;
    const float* mrow = mask + (size_t)bz * SS * SS;
    bf16* out = sc + (size_t)bz * SS * SS;
    const float scale = 0.03125f;  // 1/sqrt(1024)
#pragma unroll
    for (int m = 0; m < 8; ++m)
#pragma unroll
        for (int n = 0; n < 4; ++n)
#pragma unroll
            for (int j = 0; j < 4; ++j) {
                const int grow = m0 + wm * 128 + m * 16 + kq * 4 + j;
                const int gcol = n0 + wn * 64 + n * 16 + lr;
                const float v = acc[m][n][j] * scale + mrow[(size_t)grow * SS + gcol];
                out[(size_t)grow * SS + gcol] = (bf16)v;
            }
}

// ---------------------------------------------------------------------------
// K4: row softmax over 2048, in place, bf16. One block per row.
// ---------------------------------------------------------------------------
__global__ __launch_bounds__(256) void softmax_kernel(bf16* __restrict__ sc)
{
    __shared__ float red[4];
    const size_t row = blockIdx.x;
    uint4* rp = (uint4*)(sc + row * (size_t)SS);
    const int tid = threadIdx.x, lane = tid & 63, wid = tid >> 6;

    const uint4 d = rp[tid];
    const unsigned int u[4] = { d.x, d.y, d.z, d.w };
    float f[8];
#pragma unroll
    for (int i = 0; i < 4; ++i) {
        union { unsigned int i_; float f_; } lo, hi;
        lo.i_ = u[i] << 16;
        hi.i_ = u[i] & 0xffff0000u;
        f[2 * i]     = lo.f_;
        f[2 * i + 1] = hi.f_;
    }

    float m = f[0];
#pragma unroll
    for (int i = 1; i < 8; ++i) m = fmaxf(m, f[i]);
#pragma unroll
    for (int o = 32; o > 0; o >>= 1) m = fmaxf(m, __shfl_xor(m, o));
    if (lane == 0) red[wid] = m;
    __syncthreads();
    m = fmaxf(fmaxf(red[0], red[1]), fmaxf(red[2], red[3]));
    __syncthreads();

    float e[8], s = 0.f;
#pragma unroll
    for (int i = 0; i < 8; ++i) { e[i] = __expf(f[i] - m); s += e[i]; }
#pragma unroll
    for (int o = 32; o > 0; o >>= 1) s += __shfl_xor(s, o);
    if (lane == 0) red[wid] = s;
    __syncthreads();
    s = red[0] + red[1] + red[2] + red[3];
    const float inv = 1.0f / s;

    unsigned int ou[4];
#pragma unroll
    for (int i = 0; i < 4; ++i) {
        union { bf16 h; unsigned short b; } a0, a1;
        a0.h = (bf16)(e[2 * i] * inv);
        a1.h = (bf16)(e[2 * i + 1] * inv);
        ou[i] = ((unsigned int)a1.b << 16) | (unsigned int)a0.b;
    }
    rp[tid] = make_uint4(ou[0], ou[1], ou[2], ou[3]);
}

// ---------------------------------------------------------------------------
// K5: out = P @ V^T. M=2048, N=1024, K=2048 per batch. fp32 out.
// BM=128 (M_REP=4), BN=256 (N_REP=4) -> 4x16x4 = 256 blocks = 1 CU-round.
// ---------------------------------------------------------------------------
__global__ __launch_bounds__(512, 2) void pv8(const bf16* __restrict__ sc,
                                              const bf16* __restrict__ vt,
                                              float* __restrict__ outp)
{
    extern __shared__ char lds[];
    int bx, by, bz; swz_block(bx, by, bz);
    const bf16* A  = sc + (size_t)bz * SS * SS;   // [2048][2048]
    const bf16* Bm = vt + (size_t)bz * EE * SS;   // [1024][2048]

    const int m0 = by * 128, n0 = bx * 256;
    const int tid = threadIdx.x;

    f32x4 acc[4][4];
#pragma unroll
    for (int m = 0; m < 4; ++m)
#pragma unroll
        for (int n = 0; n < 4; ++n) { acc[m][n][0] = 0.f; acc[m][n][1] = 0.f; acc[m][n][2] = 0.f; acc[m][n][3] = 0.f; }

    kloopX<4, 4>(A, Bm, SS, SS, SS / 32, lds, m0, n0, tid, acc);

    const int lane = tid & 63, w = tid >> 6, wm = w >> 2, wn = w & 3;
    const int lr = lane & 15, kq = lane >> 4;
#pragma unroll
    for (int m = 0; m < 4; ++m)
#pragma unroll
        for (int n = 0; n < 4; ++n)
#pragma unroll
            for (int j = 0; j < 4; ++j) {
                const int grow = m0 + wm * 64 + m * 16 + kq * 4 + j;
                const int gcol = n0 + wn * 64 + n * 16 + lr;
                outp[((size_t)bz * SS + grow) * EE + gcol] = acc[m][n][j];
            }
}

// ---------------------------------------------------------------------------
// Host launcher
// Inputs: 0 query 1 key 2 value 3 attn_mask 4 Wq 5 bq 6 Wk 7 bk 8 Wv 9 bv
// WS: qb | kb | vb | vt | sc | Wc. Aliases: qc=vt, kc=sc[0:], vc=sc[half:].
// ---------------------------------------------------------------------------
extern "C" void kernel_launch(void* const* d_in, const int* in_sizes, int n_in,
                              void* d_out, int out_size, void* d_ws, size_t ws_size,
                              hipStream_t stream)
{
    const float* query = (const float*)d_in[0];
    const float* key_  = (const float*)d_in[1];
    const float* value = (const float*)d_in[2];
    const float* mask  = (const float*)d_in[3];
    const float* Wq = (const float*)d_in[4];
    const float* bq = (const float*)d_in[5];
    const float* Wk = (const float*)d_in[6];
    const float* bk = (const float*)d_in[7];
    const float* Wv = (const float*)d_in[8];
    const float* bv = (const float*)d_in[9];
    float* outp = (float*)d_out;

    char* ws = (char*)d_ws;
    const size_t QKV = (size_t)NB * SS * EE * 2;   // 16,777,216 B
    const size_t SCB = (size_t)NB * SS * SS * 2;   // 33,554,432 B
    const size_t WCB = (size_t)3 * EE * EE * 2;    //  6,291,456 B
    if (ws_size < 4 * QKV + SCB + WCB) return;

    bf16* qb = (bf16*)(ws);
    bf16* kb = (bf16*)(ws + QKV);
    bf16* vb = (bf16*)(ws + 2 * QKV);
    bf16* vt = (bf16*)(ws + 3 * QKV);
    bf16* sc = (bf16*)(ws + 4 * QKV);
    bf16* Wc = (bf16*)(ws + 4 * QKV + SCB);
    bf16* qc = vt;                       // lifetime ends before transpose
    bf16* kc = sc;                       // lifetime ends before scores
    bf16* vc = (bf16*)(ws + 5 * QKV);

    // dynamic LDS: 4 rotating buffers of (BM+BN)*64 B
    const int LDS_PROJ   = 4 * (256 + 128) * 64;   //  98304
    const int LDS_SCORES = 4 * (256 + 256) * 64;   // 131072
    const int LDS_PV     = 4 * (128 + 256) * 64;   //  98304
    (void)hipFuncSetAttribute((const void*)proj8,   hipFuncAttributeMaxDynamicSharedMemorySize, LDS_PROJ);
    (void)hipFuncSetAttribute((const void*)scores8, hipFuncAttributeMaxDynamicSharedMemorySize, LDS_SCORES);
    (void)hipFuncSetAttribute((const void*)pv8,     hipFuncAttributeMaxDynamicSharedMemorySize, LDS_PV);

    dim3 blk(256), blk5(512);
    const unsigned NQKV = (unsigned)NB * SS * EE;  // 8,388,608
    const unsigned NW   = (unsigned)EE * EE;       // 1,048,576
    cvt3_kernel<<<dim3(NQKV / (256 * 8), 3), blk, 0, stream>>>(
        query, key_, value, qc, kc, vc, NQKV);
    cvt3_kernel<<<dim3(NW / (256 * 8), 3), blk, 0, stream>>>(
        Wq, Wk, Wv, Wc, Wc + (size_t)EE * EE, Wc + 2 * (size_t)EE * EE, NW);

    proj8<<<dim3(EE / 128, (NB * SS) / 256, 3), blk5, LDS_PROJ, stream>>>(
        qc, kc, vc, Wc, bq, bk, bv, qb, kb, vb);
    transpose_kernel<<<dim3(SS / 64, EE / 64, NB), blk, 0, stream>>>(vb, vt);
    scores8<<<dim3(SS / 256, SS / 256, NB), blk5, LDS_SCORES, stream>>>(qb, kb, mask, sc);
    softmax_kernel<<<dim3(NB * SS), blk, 0, stream>>>(sc);
    pv8<<<dim3(EE / 256, SS / 128, NB), blk5, LDS_PV, stream>>>(sc, vt, outp);
}

// Round 6
// 201.109 us; speedup vs baseline: 1.0461x; 1.0461x over previous
//
#include <hip/hip_runtime.h>
#include <cstdint>
#include <cstddef>

typedef __bf16 bf16;
typedef __bf16 bf16x8 __attribute__((ext_vector_type(8)));
typedef float  f32x4  __attribute__((ext_vector_type(4)));

#define NB 4
#define SS 2048
#define EE 1024

// ---------------------------------------------------------------------------
// Async global->LDS, 16 B/lane. LDS dest = wave-uniform base + lane*16
// (m104/m108); global src is per-lane (swizzle applied on the src side).
// ---------------------------------------------------------------------------
static __device__ __forceinline__ void glds16(const bf16* g, void* l)
{
    __builtin_amdgcn_global_load_lds(
        (const __attribute__((address_space(1))) unsigned int*)g,
        (__attribute__((address_space(3))) unsigned int*)l,
        16, 0, 0);
}

// Bijective XCD-aware swizzle (all grids here have nwg % 8 == 0).
static __device__ __forceinline__ void swz_block(int& bx, int& by, int& bz)
{
    const int nx = gridDim.x, ny = gridDim.y;
    const int nwg = nx * ny * gridDim.z;
    int lin = blockIdx.x + nx * (blockIdx.y + ny * blockIdx.z);
    const int per = nwg >> 3;
    lin = (lin & 7) * per + (lin >> 3);
    bz = lin / (nx * ny);
    const int r = lin - bz * nx * ny;
    by = r / nx;
    bx = r - by * nx;
}

// ---------------------------------------------------------------------------
// m201-style 4-phase K-loop. BK=64, BN=256, BM=32*MR. 512 threads = 8 waves.
// Per-wave output 128x64 (MR=8) or 64x64 scattered quadrants (MR=4).
//
// LDS: half-tile ring. A: 4 slots of [RA=MR*16 rows][64 k]; B: 4 slots of
// [128][64]. Slot for (tile t, half h) = (2t+h)&3. Row = 128 B = 8 chunks of
// 16 B; chunk swizzle: physical = logical ^ (row&7). Staging keeps the LDS
// dest linear and inverse-swizzles the GLOBAL source (rule 21); frag reads
// XOR the chunk -> per quarter-wave 16 lanes cover 8 chunk-columns at 2-way
// (free, m136; measured 0 conflicts in r3/r5 with the same involution).
//
// Phases per K-tile (C-quadrants of the 256-col block, mh/nh halves):
//   p0 (0,0): read A-half0 frags (MR) + B-half0 frags (4) | stage B1(t+1)
//   p1 (0,1): read B-half1 frags (4)   [A regs reused]    | stage A0(t+2)
//   p2 (1,0): read A-half1 frags (MR)  [B0 regs reused]   | stage B0(t+2)
//   p3 (1,1): no reads                 [A,B1 reused]      | stage A1(t+2)
// Each phase: reads | stage | barrier | lgkmcnt(0) | setprio(1) | 2*MR MFMA |
// setprio(0) | barrier. Tile end: vmcnt(NVM) (3 half-tiles stay in flight,
// T4: never drain in-loop) + barrier. Every stage overwrites a slot whose
// LDS reads completed in an EARLIER phase (no latency-dependent race).
// Tail: clamped tile index restages identical data into the same slot
// (benign) keeping vmcnt accounting constant; vmcnt(0) drains after loop.
// ---------------------------------------------------------------------------
template<int MR>
static __device__ __forceinline__ void kloop4(
    const bf16* __restrict__ A, const bf16* __restrict__ Bm,
    int lda, int ldb, int nt, char* lds, int m0, int n0, int tid,
    f32x4 acc[MR][4])
{
    constexpr int RA    = MR * 16;       // rows per A half-tile
    constexpr int SZA   = RA * 128;      // bytes per A half-slot
    constexpr int LA_H  = SZA / 8192;    // glds16 per A half (1 or 2)
    constexpr int ABASE = 4 * SZA;
    constexpr int SZB   = 16384;
    constexpr int MH    = MR / 2;

    const int lane = tid & 63, w = tid >> 6;
    const int wm = w >> 2, wn = w & 3;
    const int lr = lane & 15, kq = lane >> 4;

    const int k0x  = ((kq ^ (lr & 7)) << 4);         // k-slice 0 chunk byte
    const int k1x  = (((4 + kq) ^ (lr & 7)) << 4);   // k-slice 1 chunk byte
    const int arow = wm * (RA / 2) * 128 + lr * 128; // + mf*2048
    const int brow = wn * 32 * 128 + lr * 128;       // + nf*2048
    const int wofs = w << 10;

    // staging source (inverse-swizzled): row = srow, chunk = (tid&7)^(srow&7)
    const int srow = tid >> 3;
    const int scol = ((tid & 7) ^ (srow & 7)) * 8;
    const bf16* pA = A  + (size_t)(m0 + srow) * lda + scol;
    const bf16* pB = Bm + (size_t)(n0 + srow) * ldb + scol;

    auto stageA = [&](int t, int h) {
        char* d = lds + ((2 * t + h) & 3) * SZA + wofs;
        const bf16* s = pA + (size_t)(h * RA) * lda + t * 64;
#pragma unroll
        for (int i = 0; i < LA_H; ++i)
            glds16(s + (size_t)(i * 64) * lda, d + i * 8192);
    };
    auto stageB = [&](int t, int h) {
        char* d = lds + ABASE + ((2 * t + h) & 3) * SZB + wofs;
        const bf16* s = pB + (size_t)(h * 128) * ldb + t * 64;
        glds16(s, d);
        glds16(s + (size_t)64 * ldb, d + 8192);
    };
    auto sync_pre = [] {
        __builtin_amdgcn_sched_barrier(0);
        __builtin_amdgcn_s_barrier();
        asm volatile("s_waitcnt lgkmcnt(0)" ::: "memory");
        __builtin_amdgcn_sched_barrier(0);
        __builtin_amdgcn_s_setprio(1);
    };
    auto sync_post = [] {
        __builtin_amdgcn_s_setprio(0);
        __builtin_amdgcn_sched_barrier(0);
        __builtin_amdgcn_s_barrier();
    };

    // prologue: tile0 complete + {A0,B0,A1}(1) in flight
    stageA(0, 0); stageA(0, 1); stageB(0, 0); stageB(0, 1);
    stageA(1, 0); stageB(1, 0); stageA(1, 1);
    if constexpr (MR == 8) asm volatile("s_waitcnt vmcnt(6)" ::: "memory");
    else                   asm volatile("s_waitcnt vmcnt(4)" ::: "memory");
    __builtin_amdgcn_sched_barrier(0);
    __builtin_amdgcn_s_barrier();

    bf16x8 af[MR], b0[4], b1[4];

#define MFMA_Q(AOFF, BOFF, BARR) \
    _Pragma("unroll") \
    for (int mf = 0; mf < MH; ++mf) \
        _Pragma("unroll") \
        for (int nf = 0; nf < 2; ++nf) { \
            acc[(AOFF) + mf][(BOFF) + nf] = __builtin_amdgcn_mfma_f32_16x16x32_bf16(af[2*mf],   BARR[2*nf],   acc[(AOFF) + mf][(BOFF) + nf], 0, 0, 0); \
            acc[(AOFF) + mf][(BOFF) + nf] = __builtin_amdgcn_mfma_f32_16x16x32_bf16(af[2*mf+1], BARR[2*nf+1], acc[(AOFF) + mf][(BOFF) + nf], 0, 0, 0); \
        }

    for (int t = 0; t < nt; ++t) {
        const int t1 = (t + 1 < nt) ? t + 1 : nt - 1;
        const int t2 = (t + 2 < nt) ? t + 2 : nt - 1;
        char* as0 = lds + ((2 * t)     & 3) * SZA;
        char* as1 = lds + ((2 * t + 1) & 3) * SZA;
        char* bs0 = lds + ABASE + ((2 * t)     & 3) * SZB;
        char* bs1 = lds + ABASE + ((2 * t + 1) & 3) * SZB;

        // ---- phase 0: quadrant (0,0)
#pragma unroll
        for (int mf = 0; mf < MH; ++mf) {
            af[2*mf]   = *(const bf16x8*)(as0 + arow + mf * 2048 + k0x);
            af[2*mf+1] = *(const bf16x8*)(as0 + arow + mf * 2048 + k1x);
        }
#pragma unroll
        for (int nf = 0; nf < 2; ++nf) {
            b0[2*nf]   = *(const bf16x8*)(bs0 + brow + nf * 2048 + k0x);
            b0[2*nf+1] = *(const bf16x8*)(bs0 + brow + nf * 2048 + k1x);
        }
        stageB(t1, 1);
        sync_pre();
        MFMA_Q(0, 0, b0)
        sync_post();

        // ---- phase 1: quadrant (0,1)  [A regs reused]
#pragma unroll
        for (int nf = 0; nf < 2; ++nf) {
            b1[2*nf]   = *(const bf16x8*)(bs1 + brow + nf * 2048 + k0x);
            b1[2*nf+1] = *(const bf16x8*)(bs1 + brow + nf * 2048 + k1x);
        }
        stageA(t2, 0);
        sync_pre();
        MFMA_Q(0, 2, b1)
        sync_post();

        // ---- phase 2: quadrant (1,0)  [B0 regs reused]
#pragma unroll
        for (int mf = 0; mf < MH; ++mf) {
            af[2*mf]   = *(const bf16x8*)(as1 + arow + mf * 2048 + k0x);
            af[2*mf+1] = *(const bf16x8*)(as1 + arow + mf * 2048 + k1x);
        }
        stageB(t2, 0);
        sync_pre();
        MFMA_Q(MH, 0, b0)
        sync_post();

        // ---- phase 3: quadrant (1,1)  [A,B1 regs reused]
        stageA(t2, 1);
        sync_pre();
        MFMA_Q(MH, 2, b1)
        __builtin_amdgcn_s_setprio(0);
        __builtin_amdgcn_sched_barrier(0);
        // tile boundary: counted vmcnt, 3 half-tiles stay in flight
        if constexpr (MR == 8) asm volatile("s_waitcnt vmcnt(6)" ::: "memory");
        else                   asm volatile("s_waitcnt vmcnt(4)" ::: "memory");
        __builtin_amdgcn_sched_barrier(0);
        __builtin_amdgcn_s_barrier();
    }
    asm volatile("s_waitcnt vmcnt(0)" ::: "memory");  // drain dummy-tail loads
#undef MFMA_Q
}

// ---------------------------------------------------------------------------
// K0: fp32 -> bf16 convert, 8 elems/thread, three tensors via blockIdx.y.
// ---------------------------------------------------------------------------
__global__ __launch_bounds__(256) void cvt3_kernel(
    const float* __restrict__ s0, const float* __restrict__ s1, const float* __restrict__ s2,
    bf16* __restrict__ d0, bf16* __restrict__ d1, bf16* __restrict__ d2, unsigned n)
{
    const float* s; bf16* d;
    if (blockIdx.y == 0)      { s = s0; d = d0; }
    else if (blockIdx.y == 1) { s = s1; d = d1; }
    else                      { s = s2; d = d2; }
    const size_t i = ((size_t)blockIdx.x * 256 + threadIdx.x) * 8;
    if (i >= n) return;
    const float4 f0 = *(const float4*)(s + i);
    const float4 f1 = *(const float4*)(s + i + 4);
    bf16x8 h;
    h[0] = (bf16)f0.x; h[1] = (bf16)f0.y; h[2] = (bf16)f0.z; h[3] = (bf16)f0.w;
    h[4] = (bf16)f1.x; h[5] = (bf16)f1.y; h[6] = (bf16)f1.z; h[7] = (bf16)f1.w;
    *(bf16x8*)(d + i) = h;
}

// ---------------------------------------------------------------------------
// K1: fused QKV projection. M=8192, N=K=1024, z selects q/k/v. MR=8:
// BM=256, BN=256 -> grid 4x32x3 = 384 blocks.
// C/D 16x16 layout: col = lane&15, row = (lane>>4)*4 + j  [m89/m91].
// ---------------------------------------------------------------------------
__global__ __launch_bounds__(512, 2) void proj8(
    const bf16* __restrict__ qc, const bf16* __restrict__ kc, const bf16* __restrict__ vc,
    const bf16* __restrict__ Wc,
    const float* __restrict__ bq, const float* __restrict__ bk, const float* __restrict__ bv,
    bf16* __restrict__ qb, bf16* __restrict__ kb, bf16* __restrict__ vb)
{
    extern __shared__ char lds[];
    int bx, by, bz; swz_block(bx, by, bz);
    const bf16* A; const float* bias; bf16* out;
    if (bz == 0)      { A = qc; bias = bq; out = qb; }
    else if (bz == 1) { A = kc; bias = bk; out = kb; }
    else              { A = vc; bias = bv; out = vb; }
    const bf16* Bm = Wc + (size_t)bz * EE * EE;

    const int m0 = by * 256, n0 = bx * 256;
    const int tid = threadIdx.x;

    f32x4 acc[8][4];
#pragma unroll
    for (int m = 0; m < 8; ++m)
#pragma unroll
        for (int n = 0; n < 4; ++n) { acc[m][n][0] = 0.f; acc[m][n][1] = 0.f; acc[m][n][2] = 0.f; acc[m][n][3] = 0.f; }

    kloop4<8>(A, Bm, EE, EE, EE / 64, lds, m0, n0, tid, acc);

    const int lane = tid & 63, w = tid >> 6, wm = w >> 2, wn = w & 3;
    const int lr = lane & 15, kq = lane >> 4;
#pragma unroll
    for (int bi = 0; bi < 4; ++bi) {
        const int nh = bi >> 1, nf = bi & 1;
        const int gcol = n0 + nh * 128 + wn * 32 + nf * 16 + lr;
        const float bb = bias[gcol];
#pragma unroll
        for (int ai = 0; ai < 8; ++ai) {
            const int mh = ai >> 2, mf = ai & 3;
#pragma unroll
            for (int j = 0; j < 4; ++j) {
                const int grow = m0 + mh * 128 + wm * 64 + mf * 16 + kq * 4 + j;
                out[(size_t)grow * EE + gcol] = (bf16)(acc[ai][bi][j] + bb);
            }
        }
    }
}

// ---------------------------------------------------------------------------
// K2: vb [b][s][e] -> vt [b][e][s]
// ---------------------------------------------------------------------------
__global__ __launch_bounds__(256) void transpose_kernel(const bf16* __restrict__ vb,
                                                        bf16* __restrict__ vt)
{
    __shared__ bf16 t[64][72];
    const int b  = blockIdx.z;
    const int s0 = blockIdx.x * 64, e0 = blockIdx.y * 64;
    const int tid = threadIdx.x;

    const bf16* src = vb + ((size_t)b * SS + s0) * EE + e0;
#pragma unroll
    for (int i = 0; i < 2; ++i) {
        const int c  = tid * 2 + i;
        const int r  = c >> 3;
        const int cc = (c & 7) * 8;
        *(uint4*)&t[r][cc] = *(const uint4*)&src[(size_t)r * EE + cc];
    }
    __syncthreads();

    bf16* dst = vt + ((size_t)b * EE + e0) * SS + s0;
    const int er  = tid >> 2;
    const int sc0 = (tid & 3) * 16;
    bf16 tmp[16];
#pragma unroll
    for (int k2 = 0; k2 < 16; ++k2) tmp[k2] = t[sc0 + k2][er];
    *(uint4*)&dst[(size_t)er * SS + sc0]     = *(uint4*)&tmp[0];
    *(uint4*)&dst[(size_t)er * SS + sc0 + 8] = *(uint4*)&tmp[8];
}

// ---------------------------------------------------------------------------
// K3: scores = (q.k)/32 + mask, bf16 out. M=N=2048, K=1024 per batch.
// MR=8: BM=BN=256 -> grid 8x8x4 = 256 blocks = 1 CU-round.
// ---------------------------------------------------------------------------
__global__ __launch_bounds__(512, 2) void scores8(const bf16* __restrict__ qb,
                                                  const bf16* __restrict__ kb,
                                                  const float* __restrict__ mask,
                                                  bf16* __restrict__ sc)
{
    extern __shared__ char lds[];
    int bx, by, bz; swz_block(bx, by, bz);
    const bf16* A  = qb + (size_t)bz * SS * EE;
    const bf16* Bm = kb + (size_t)bz * SS * EE;

    const int m0 = by * 256, n0 = bx * 256;
    const int tid = threadIdx.x;

    f32x4 acc[8][4];
#pragma unroll
    for (int m = 0; m < 8; ++m)
#pragma unroll
        for (int n = 0; n < 4; ++n) { acc[m][n][0] = 0.f; acc[m][n][1] = 0.f; acc[m][n][2] = 0.f; acc[m][n][3] = 0.f; }

    kloop4<8>(A, Bm, EE, EE, EE / 64, lds, m0, n0, tid, acc);

    const int lane = tid & 63, w = tid >> 6, wm = w >> 2, wn = w & 3;
    const int lr = lane & 15, kq = lane >> 4;
    const float* mrow = mask + (size_t)bz * SS * SS;
    bf16* out = sc + (size_t)bz * SS * SS;
    const float scale = 0.03125f;  // 1/sqrt(1024)
#pragma unroll
    for (int ai = 0; ai < 8; ++ai) {
        const int mh = ai >> 2, mf = ai & 3;
#pragma unroll
        for (int bi = 0; bi < 4; ++bi) {
            const int nh = bi >> 1, nf = bi & 1;
            const int gcol = n0 + nh * 128 + wn * 32 + nf * 16 + lr;
#pragma unroll
            for (int j = 0; j < 4; ++j) {
                const int grow = m0 + mh * 128 + wm * 64 + mf * 16 + kq * 4 + j;
                const float v = acc[ai][bi][j] * scale + mrow[(size_t)grow * SS + gcol];
                out[(size_t)grow * SS + gcol] = (bf16)v;
            }
        }
    }
}

// ---------------------------------------------------------------------------
// K4: row softmax over 2048, in place, bf16. One block per row.
// ---------------------------------------------------------------------------
__global__ __launch_bounds__(256) void softmax_kernel(bf16* __restrict__ sc)
{
    __shared__ float red[4];
    const size_t row = blockIdx.x;
    uint4* rp = (uint4*)(sc + row * (size_t)SS);
    const int tid = threadIdx.x, lane = tid & 63, wid = tid >> 6;

    const uint4 d = rp[tid];
    const unsigned int u[4] = { d.x, d.y, d.z, d.w };
    float f[8];
#pragma unroll
    for (int i = 0; i < 4; ++i) {
        union { unsigned int i_; float f_; } lo, hi;
        lo.i_ = u[i] << 16;
        hi.i_ = u[i] & 0xffff0000u;
        f[2 * i]     = lo.f_;
        f[2 * i + 1] = hi.f_;
    }

    float m = f[0];
#pragma unroll
    for (int i = 1; i < 8; ++i) m = fmaxf(m, f[i]);
#pragma unroll
    for (int o = 32; o > 0; o >>= 1) m = fmaxf(m, __shfl_xor(m, o));
    if (lane == 0) red[wid] = m;
    __syncthreads();
    m = fmaxf(fmaxf(red[0], red[1]), fmaxf(red[2], red[3]));
    __syncthreads();

    float e[8], s = 0.f;
#pragma unroll
    for (int i = 0; i < 8; ++i) { e[i] = __expf(f[i] - m); s += e[i]; }
#pragma unroll
    for (int o = 32; o > 0; o >>= 1) s += __shfl_xor(s, o);
    if (lane == 0) red[wid] = s;
    __syncthreads();
    s = red[0] + red[1] + red[2] + red[3];
    const float inv = 1.0f / s;

    unsigned int ou[4];
#pragma unroll
    for (int i = 0; i < 4; ++i) {
        union { bf16 h; unsigned short b; } a0, a1;
        a0.h = (bf16)(e[2 * i] * inv);
        a1.h = (bf16)(e[2 * i + 1] * inv);
        ou[i] = ((unsigned int)a1.b << 16) | (unsigned int)a0.b;
    }
    rp[tid] = make_uint4(ou[0], ou[1], ou[2], ou[3]);
}

// ---------------------------------------------------------------------------
// K5: out = P @ V^T. M=2048, N=1024, K=2048 per batch. fp32 out.
// MR=4: BM=128, BN=256 -> grid 4x16x4 = 256 blocks = 1 CU-round.
// ---------------------------------------------------------------------------
__global__ __launch_bounds__(512, 2) void pv8(const bf16* __restrict__ sc,
                                              const bf16* __restrict__ vt,
                                              float* __restrict__ outp)
{
    extern __shared__ char lds[];
    int bx, by, bz; swz_block(bx, by, bz);
    const bf16* A  = sc + (size_t)bz * SS * SS;   // [2048][2048]
    const bf16* Bm = vt + (size_t)bz * EE * SS;   // [1024][2048]

    const int m0 = by * 128, n0 = bx * 256;
    const int tid = threadIdx.x;

    f32x4 acc[4][4];
#pragma unroll
    for (int m = 0; m < 4; ++m)
#pragma unroll
        for (int n = 0; n < 4; ++n) { acc[m][n][0] = 0.f; acc[m][n][1] = 0.f; acc[m][n][2] = 0.f; acc[m][n][3] = 0.f; }

    kloop4<4>(A, Bm, SS, SS, SS / 64, lds, m0, n0, tid, acc);

    const int lane = tid & 63, w = tid >> 6, wm = w >> 2, wn = w & 3;
    const int lr = lane & 15, kq = lane >> 4;
#pragma unroll
    for (int ai = 0; ai < 4; ++ai) {
        const int mh = ai >> 1, mf = ai & 1;
#pragma unroll
        for (int bi = 0; bi < 4; ++bi) {
            const int nh = bi >> 1, nf = bi & 1;
            const int gcol = n0 + nh * 128 + wn * 32 + nf * 16 + lr;
#pragma unroll
            for (int j = 0; j < 4; ++j) {
                const int grow = m0 + mh * 64 + wm * 32 + mf * 16 + kq * 4 + j;
                outp[((size_t)bz * SS + grow) * EE + gcol] = acc[ai][bi][j];
            }
        }
    }
}

// ---------------------------------------------------------------------------
// Host launcher
// Inputs: 0 query 1 key 2 value 3 attn_mask 4 Wq 5 bq 6 Wk 7 bk 8 Wv 9 bv
// WS: qb | kb | vb | vt | sc | Wc. Aliases: qc=vt, kc=sc[0:], vc=sc[half:].
// ---------------------------------------------------------------------------
extern "C" void kernel_launch(void* const* d_in, const int* in_sizes, int n_in,
                              void* d_out, int out_size, void* d_ws, size_t ws_size,
                              hipStream_t stream)
{
    const float* query = (const float*)d_in[0];
    const float* key_  = (const float*)d_in[1];
    const float* value = (const float*)d_in[2];
    const float* mask  = (const float*)d_in[3];
    const float* Wq = (const float*)d_in[4];
    const float* bq = (const float*)d_in[5];
    const float* Wk = (const float*)d_in[6];
    const float* bk = (const float*)d_in[7];
    const float* Wv = (const float*)d_in[8];
    const float* bv = (const float*)d_in[9];
    float* outp = (float*)d_out;

    char* ws = (char*)d_ws;
    const size_t QKV = (size_t)NB * SS * EE * 2;   // 16,777,216 B
    const size_t SCB = (size_t)NB * SS * SS * 2;   // 33,554,432 B
    const size_t WCB = (size_t)3 * EE * EE * 2;    //  6,291,456 B
    if (ws_size < 4 * QKV + SCB + WCB) return;

    bf16* qb = (bf16*)(ws);
    bf16* kb = (bf16*)(ws + QKV);
    bf16* vb = (bf16*)(ws + 2 * QKV);
    bf16* vt = (bf16*)(ws + 3 * QKV);
    bf16* sc = (bf16*)(ws + 4 * QKV);
    bf16* Wc = (bf16*)(ws + 4 * QKV + SCB);
    bf16* qc = vt;                       // lifetime ends before transpose
    bf16* kc = sc;                       // lifetime ends before scores
    bf16* vc = (bf16*)(ws + 5 * QKV);

    // dynamic LDS: 4 A half-slots + 4 B half-slots
    const int LDS8 = 4 * (128 * 128) + 4 * 16384;  // 131072 (proj, scores)
    const int LDS4 = 4 * (64 * 128)  + 4 * 16384;  //  98304 (pv)
    (void)hipFuncSetAttribute((const void*)proj8,   hipFuncAttributeMaxDynamicSharedMemorySize, LDS8);
    (void)hipFuncSetAttribute((const void*)scores8, hipFuncAttributeMaxDynamicSharedMemorySize, LDS8);
    (void)hipFuncSetAttribute((const void*)pv8,     hipFuncAttributeMaxDynamicSharedMemorySize, LDS4);

    dim3 blk(256), blk5(512);
    const unsigned NQKV = (unsigned)NB * SS * EE;  // 8,388,608
    const unsigned NW   = (unsigned)EE * EE;       // 1,048,576
    cvt3_kernel<<<dim3(NQKV / (256 * 8), 3), blk, 0, stream>>>(
        query, key_, value, qc, kc, vc, NQKV);
    cvt3_kernel<<<dim3(NW / (256 * 8), 3), blk, 0, stream>>>(
        Wq, Wk, Wv, Wc, Wc + (size_t)EE * EE, Wc + 2 * (size_t)EE * EE, NW);

    proj8<<<dim3(EE / 256, (NB * SS) / 256, 3), blk5, LDS8, stream>>>(
        qc, kc, vc, Wc, bq, bk, bv, qb, kb, vb);
    transpose_kernel<<<dim3(SS / 64, EE / 64, NB), blk, 0, stream>>>(vb, vt);
    scores8<<<dim3(SS / 256, SS / 256, NB), blk5, LDS8, stream>>>(qb, kb, mask, sc);
    softmax_kernel<<<dim3(NB * SS), blk, 0, stream>>>(sc);
    pv8<<<dim3(EE / 256, SS / 128, NB), blk5, LDS4, stream>>>(sc, vt, outp);
}